// Round 18
// baseline (255.077 us; speedup 1.0000x reference)
//
#include <hip/hip_runtime.h>
#include <math.h>

#define NNODES  100000
#define NEDGES  3200000
#define NGRAPHS 1024
#define BNODES  196                              // nodes per bucket
#define NBUCK   ((NNODES + BNODES - 1) / BNODES) // 511
#define SCAP    12288                            // staging capacity per bucket
#define CHUNK   4096
#define NCHUNKS ((NEDGES + CHUNK - 1) / CHUNK)   // 782

typedef int iv4 __attribute__((ext_vector_type(4)));
typedef float fv2 __attribute__((ext_vector_type(2)));

#if defined(__has_builtin)
#if __has_builtin(__builtin_amdgcn_cvt_pk_f32_fp8) && __has_builtin(__builtin_amdgcn_cvt_pk_fp8_f32)
#define HW_FP8 1
#endif
#endif

// ---- bf16x2 pack/unpack (RNE) ----
__device__ __forceinline__ unsigned bf16pair(float a, float b) {
    unsigned ua = __float_as_uint(a), ub = __float_as_uint(b);
    ua += 0x7fffu + ((ua >> 16) & 1u);
    ub += 0x7fffu + ((ub >> 16) & 1u);
    return (ua >> 16) | (ub & 0xffff0000u);
}
__device__ __forceinline__ float bflo(unsigned u) { return __uint_as_float(u << 16); }
__device__ __forceinline__ float bfhi(unsigned u) { return __uint_as_float(u & 0xffff0000u); }

// ---- fp8 e4m3 (OCP) manual fallback ----
__device__ __forceinline__ unsigned fp8_of(float v) {
    unsigned s = (__float_as_uint(v) >> 24) & 0x80u;
    float a = fminf(fabsf(v), 448.f);
    unsigned ub = __float_as_uint(a);
    unsigned lsb = (ub >> 20) & 1u;
    ub += 0x0007FFFFu + lsb;
    int em = (int)(ub >> 20) - (120 << 3);
    if (em < 1) return s;
    if (em > 0x7E) em = 0x7E;
    return s | (unsigned)em;
}
__device__ __forceinline__ float fp8_to_f(unsigned b) {
    unsigned em = b & 0x7Fu;
    unsigned s = (b & 0x80u) << 24;
    float f = __uint_as_float(s | ((em + 0x3C0u) << 20));
    return (em >= 8u) ? f : 0.f;
}
__device__ __forceinline__ void fp8x4_to_f(unsigned w, float& f0, float& f1, float& f2, float& f3) {
#ifdef HW_FP8
    fv2 lo = __builtin_amdgcn_cvt_pk_f32_fp8((int)w, false);
    fv2 hi = __builtin_amdgcn_cvt_pk_f32_fp8((int)w, true);
    f0 = lo.x; f1 = lo.y; f2 = hi.x; f3 = hi.y;
#else
    f0 = fp8_to_f(w & 0xFFu);
    f1 = fp8_to_f((w >> 8) & 0xFFu);
    f2 = fp8_to_f((w >> 16) & 0xFFu);
    f3 = fp8_to_f(w >> 24);
#endif
}
__device__ __forceinline__ unsigned fp8x4_pack(float a, float b, float c, float d) {
    a = fminf(fmaxf(a, -448.f), 448.f);
    b = fminf(fmaxf(b, -448.f), 448.f);
    c = fminf(fmaxf(c, -448.f), 448.f);
    d = fminf(fmaxf(d, -448.f), 448.f);
#ifdef HW_FP8
    int w = __builtin_amdgcn_cvt_pk_fp8_f32(a, b, 0, false);
    w = __builtin_amdgcn_cvt_pk_fp8_f32(c, d, w, true);
    return (unsigned)w;
#else
    return fp8_of(a) | (fp8_of(b) << 8) | (fp8_of(c) << 16) | (fp8_of(d) << 24);
#endif
}

// ---------------- init ----------------

__global__ void zero4_kernel(int4* p, int nvec) {
    int i = blockIdx.x * blockDim.x + threadIdx.x;
    if (i < nvec) p[i] = make_int4(0, 0, 0, 0);
}

// ---------------- binA: LDS-staged bucket sort with ordered copy ----------------

__global__ void binA_kernel(const int* __restrict__ src, const int* __restrict__ dst,
                            int* __restrict__ bucketCur, int* __restrict__ stage) {
    __shared__ int lcnt[NBUCK + 1];
    __shared__ int boff[NBUCK + 1];
    __shared__ int gbase[NBUCK + 1];
    __shared__ int cur[NBUCK + 1];
    __shared__ int ssum[256];
    __shared__ int packed[CHUNK];
    __shared__ unsigned short bof[CHUNK];
    int tid = threadIdx.x;
    int beg = blockIdx.x * CHUNK;
    int end = beg + CHUNK; if (end > NEDGES) end = NEDGES;
    int cnt = end - beg;

    for (int i = tid; i <= NBUCK; i += 256) lcnt[i] = 0;
    __syncthreads();

    int ent[16];
    int bk[16];
#pragma unroll
    for (int it = 0; it < 4; ++it) {
        int e0 = beg + tid * 4 + it * 1024;
        if (e0 < end) {
            iv4 d4 = __builtin_nontemporal_load((const iv4*)(dst + e0));
            iv4 s4 = __builtin_nontemporal_load((const iv4*)(src + e0));
            int b;
            b = d4.x / BNODES; ent[it*4+0] = s4.x | ((d4.x - b*BNODES) << 17); bk[it*4+0] = b; atomicAdd(&lcnt[b], 1);
            b = d4.y / BNODES; ent[it*4+1] = s4.y | ((d4.y - b*BNODES) << 17); bk[it*4+1] = b; atomicAdd(&lcnt[b], 1);
            b = d4.z / BNODES; ent[it*4+2] = s4.z | ((d4.z - b*BNODES) << 17); bk[it*4+2] = b; atomicAdd(&lcnt[b], 1);
            b = d4.w / BNODES; ent[it*4+3] = s4.w | ((d4.w - b*BNODES) << 17); bk[it*4+3] = b; atomicAdd(&lcnt[b], 1);
        } else {
            bk[it*4+0] = -1; bk[it*4+1] = -1; bk[it*4+2] = -1; bk[it*4+3] = -1;
            ent[it*4+0] = 0; ent[it*4+1] = 0; ent[it*4+2] = 0; ent[it*4+3] = 0;
        }
    }
    __syncthreads();

    int b0 = 2 * tid, b1 = 2 * tid + 1;
    int c0 = lcnt[b0];
    int c1 = (b1 < NBUCK) ? lcnt[b1] : 0;
    int sum = c0 + c1;
    ssum[tid] = sum;
    __syncthreads();
    for (int o = 1; o < 256; o <<= 1) {
        int t = (tid >= o) ? ssum[tid - o] : 0;
        __syncthreads();
        ssum[tid] += t;
        __syncthreads();
    }
    int excl = ssum[tid] - sum;
    boff[b0] = excl; cur[b0] = excl;
    if (b1 < NBUCK) { boff[b1] = excl + c0; cur[b1] = excl + c0; }
    if (c0 > 0) gbase[b0] = atomicAdd(&bucketCur[b0], c0);
    if (b1 < NBUCK && c1 > 0) gbase[b1] = atomicAdd(&bucketCur[b1], c1);
    __syncthreads();

#pragma unroll
    for (int k = 0; k < 16; ++k) {
        int b = bk[k];
        if (b >= 0) {
            int p = atomicAdd(&cur[b], 1);
            packed[p] = ent[k];
            bof[p] = (unsigned short)b;
        }
    }
    __syncthreads();

    for (int i = tid; i < cnt; i += 256) {
        int b = bof[i];
        int addr = b * SCAP + gbase[b] + (i - boff[b]);
        stage[addr] = packed[i];
    }
}

// ---------------- scanE ----------------

__global__ void scanE_kernel(const int* __restrict__ bucketCur, int* __restrict__ ebase) {
    int lane = threadIdx.x;          // 64 lanes
    int run = 0;
    for (int base = 0; base < NBUCK; base += 64) {
        int idx = base + lane;
        int own = (idx < NBUCK) ? bucketCur[idx] : 0;
        int v = own;
        for (int o = 1; o < 64; o <<= 1) {
            int t = __shfl_up(v, o, 64);
            if (lane >= o) v += t;
        }
        if (idx < NBUCK) ebase[idx] = run + v - own;
        run += __shfl(v, 63, 64);
    }
}

// ---------------- binB: per-bucket fine sort + rowptr/rowend/dinv/xs ----------------

__global__ void binB_kernel(const int* __restrict__ bucketCur, const int* __restrict__ ebase,
                            const int* __restrict__ stage, const float2* __restrict__ x,
                            int* __restrict__ entries, int* __restrict__ rowptr,
                            int* __restrict__ rowend, float* __restrict__ dinv,
                            unsigned* __restrict__ xs) {
    __shared__ int s[256];
    __shared__ int ncur[256];
    __shared__ float ndinv[256];
    int b = blockIdx.x;
    int cntE = bucketCur[b];
    int eb = ebase[b];
    int nlo = b * BNODES;
    int nn = NNODES - nlo; if (nn > BNODES) nn = BNODES;
    int sb = b * SCAP;
    int tid = threadIdx.x;

    s[tid] = 0;
    __syncthreads();
    for (int e = tid; e < cntE; e += 256) {
        unsigned w = (unsigned)stage[sb + e];
        atomicAdd(&s[w >> 17], 1);
    }
    __syncthreads();
    int v = s[tid];
    for (int o = 1; o < 256; o <<= 1) {
        int t = (tid >= o) ? s[tid - o] : 0;
        __syncthreads();
        s[tid] += t;
        __syncthreads();
    }
    int excl = s[tid] - v;
    ncur[tid] = excl;
    if (tid < nn) {
        rowptr[nlo + tid] = eb + excl;
        rowend[nlo + tid] = eb + excl + v;
        float di = rsqrtf((float)(v + 1));   // +1 self-loop
        dinv[nlo + tid] = di;
        ndinv[tid] = di;
    }
    __syncthreads();
    for (int i = tid; i < nn * 8; i += 256) {
        int node = i >> 3, w = i & 7;
        float2 v2 = x[(size_t)(nlo + node) * 8 + w];
        float di = ndinv[node];
        xs[(nlo + node) * 8 + w] = bf16pair(v2.x * di, v2.y * di);
    }
    for (int e = tid; e < cntE; e += 256) {
        unsigned w = (unsigned)stage[sb + e];
        int dl = w >> 17;
        int slot = atomicAdd(&ncur[dl], 1);
        entries[eb + slot] = (int)(w & 0x1FFFFu);
    }
}

// ---------------- fused gather1 + node MLP (LDS row transpose) ----------------
// 32 nodes/block, 8 lanes/node. Per 8-edge chunk: each lane loads one FULL row
// (2x uint4 = 2 addresses instead of 8), wave-local LDS transpose, column reads.

union ShG1 {
    float h1s[32][65];          // 8320 B (phase B/C)
    unsigned scr[4][8][68];     // 8704 B (gather transpose; 68-word stride breaks banks)
};

__global__ void gather1_mlp_kernel(const int* __restrict__ entries, const int* __restrict__ rowptr,
                                   const int* __restrict__ rowend, const float* __restrict__ dinv,
                                   const unsigned* __restrict__ xs,
                                   const float* __restrict__ W1, const float* __restrict__ b1,
                                   const float* __restrict__ W2, unsigned* __restrict__ hm2f) {
    __shared__ float w1s[16 * 64];   // 4 KB
    __shared__ float w2s[64 * 32];   // 8 KB
    __shared__ float bb1[64];
    __shared__ float axs[32][17];    // +1 pad
    __shared__ __align__(16) ShG1 u;
    int tid = threadIdx.x;
    for (int i = tid; i < 16 * 64; i += 256) w1s[i] = W1[i];
    for (int i = tid; i < 64 * 32; i += 256) w2s[i] = W2[i];
    if (tid < 64) bb1[tid] = b1[tid];

    int t = blockIdx.x * 256 + tid;
    int n = t >> 3, lane = t & 7;
    int nl = tid >> 3;               // node-local 0..31
    unsigned* scr = &u.scr[tid >> 6][(tid >> 3) & 7][0];   // wave-private per-node scratch
    int beg = rowptr[n], end = rowend[n];
    unsigned self = xs[n * 8 + lane];
    float a0 = bflo(self), a1 = bfhi(self);

    int base = beg;
    for (; base + 8 <= end; base += 8) {
        int s = __builtin_nontemporal_load(entries + base + lane);
        uint4 lo = ((const uint4*)xs)[s * 2];
        uint4 hi = ((const uint4*)xs)[s * 2 + 1];
        *(uint4*)(scr + lane * 8)     = lo;
        *(uint4*)(scr + lane * 8 + 4) = hi;
        asm volatile("s_waitcnt lgkmcnt(0)" ::: "memory");   // cross-lane LDS visibility
#pragma unroll
        for (int j = 0; j < 8; ++j) {
            unsigned v = scr[j * 8 + lane];
            a0 += bflo(v); a1 += bfhi(v);
        }
        asm volatile("" ::: "memory");                       // WAR fence vs next iter's writes
    }
    {
        int m = end - base;
        if (m > 0) {
            int s = (lane < m) ? __builtin_nontemporal_load(entries + base + lane) : 0;
            for (int j = 0; j < m; ++j) {
                unsigned v = xs[__shfl(s, j, 8) * 8 + lane];
                a0 += bflo(v); a1 += bfhi(v);
            }
        }
    }
    float di = dinv[n];
    axs[nl][lane * 2]     = a0 * di;
    axs[nl][lane * 2 + 1] = a1 * di;
    __syncthreads();

    // phase B: h1[j] for j = lane*8 .. +7
    {
        int j0 = lane * 8;
        float h[8];
#pragma unroll
        for (int jj = 0; jj < 8; ++jj) h[jj] = bb1[j0 + jj];
#pragma unroll
        for (int k = 0; k < 16; ++k) {
            float a = axs[nl][k];
            const float* wr = w1s + k * 64 + j0;
#pragma unroll
            for (int jj = 0; jj < 8; ++jj) h[jj] += a * wr[jj];
        }
#pragma unroll
        for (int jj = 0; jj < 8; ++jj) u.h1s[nl][j0 + jj] = fmaxf(h[jj], 0.f);
    }
    __syncthreads();

    // phase C: h2[j] for j = lane*4 .. +3, pack fp8 word
    {
        int j0 = lane * 4;
        float c[4] = {0.f, 0.f, 0.f, 0.f};
#pragma unroll
        for (int k = 0; k < 64; ++k) {
            float hv = u.h1s[nl][k];
            const float* wr = w2s + k * 32 + j0;
#pragma unroll
            for (int jj = 0; jj < 4; ++jj) c[jj] += hv * wr[jj];
        }
        float sc = di * 64.f;                   // x64 pre-scale for fp8
        hm2f[n * 8 + lane] = fp8x4_pack(c[0] * sc, c[1] * sc, c[2] * sc, c[3] * sc);
    }
}

// ---------------- gather 2 + LDS-pooled mean-pool (LDS row transpose) ----------------

__global__ void gather2_pool_kernel(const int* __restrict__ entries, const int* __restrict__ rowptr,
                                    const int* __restrict__ rowend, const float* __restrict__ dinv,
                                    const unsigned* __restrict__ hm2f, const float4* __restrict__ b2,
                                    const int* __restrict__ batch,
                                    float* __restrict__ psum, float* __restrict__ pcnt) {
    __shared__ float lps[8][32];   // per-block partial psum, graph-relative
    __shared__ float lpc[8];
    __shared__ __align__(16) unsigned scrA[4][8][68];   // wave-private transpose scratch
    int tid = threadIdx.x;
    ((float*)lps)[tid] = 0.f;
    if (tid < 8) lpc[tid] = 0.f;

    int t = blockIdx.x * 256 + tid;
    int n = t >> 3, lane = t & 7;
    unsigned* scr = &scrA[tid >> 6][(tid >> 3) & 7][0];
    int g0 = batch[(blockIdx.x * 256) >> 3];
    int beg = rowptr[n], end = rowend[n];
    unsigned self = hm2f[n * 8 + lane];
    float a0, a1, a2, a3;
    fp8x4_to_f(self, a0, a1, a2, a3);
    __syncthreads();   // LDS zeros visible before any LDS atomic

    int base = beg;
    for (; base + 8 <= end; base += 8) {
        int s = __builtin_nontemporal_load(entries + base + lane);
        uint4 lo = ((const uint4*)hm2f)[s * 2];
        uint4 hi = ((const uint4*)hm2f)[s * 2 + 1];
        *(uint4*)(scr + lane * 8)     = lo;
        *(uint4*)(scr + lane * 8 + 4) = hi;
        asm volatile("s_waitcnt lgkmcnt(0)" ::: "memory");
#pragma unroll
        for (int j = 0; j < 8; ++j) {
            unsigned v = scr[j * 8 + lane];
            float f0, f1, f2, f3;
            fp8x4_to_f(v, f0, f1, f2, f3);
            a0 += f0; a1 += f1; a2 += f2; a3 += f3;
        }
        asm volatile("" ::: "memory");
    }
    {
        int m = end - base;
        if (m > 0) {
            int s = (lane < m) ? __builtin_nontemporal_load(entries + base + lane) : 0;
            for (int j = 0; j < m; ++j) {
                unsigned v = hm2f[__shfl(s, j, 8) * 8 + lane];
                float f0, f1, f2, f3;
                fp8x4_to_f(v, f0, f1, f2, f3);
                a0 += f0; a1 += f1; a2 += f2; a3 += f3;
            }
        }
    }
    float sc = dinv[n] * (1.0f / 64.f);         // undo x64 pre-scale
    float4 bb = b2[lane];
    float v0 = fmaxf(a0 * sc + bb.x, 0.f);
    float v1 = fmaxf(a1 * sc + bb.y, 0.f);
    float v2 = fmaxf(a2 * sc + bb.z, 0.f);
    float v3 = fmaxf(a3 * sc + bb.w, 0.f);
    int g = batch[n];
    int gr = g - g0;
    if (gr < 8) {
        float* pg = &lps[gr][lane * 4];
        atomicAdd(pg + 0, v0);
        atomicAdd(pg + 1, v1);
        atomicAdd(pg + 2, v2);
        atomicAdd(pg + 3, v3);
        if (lane == 0) atomicAdd(&lpc[gr], 1.0f);
    } else {
        float* pg = psum + g * 32 + lane * 4;
        atomicAdd(pg + 0, v0);
        atomicAdd(pg + 1, v1);
        atomicAdd(pg + 2, v2);
        atomicAdd(pg + 3, v3);
        if (lane == 0) atomicAdd(&pcnt[g], 1.0f);
    }
    __syncthreads();
    int grf = tid >> 5, f = tid & 31;
    float v = lps[grf][f];
    if (v != 0.f) atomicAdd(&psum[(g0 + grf) * 32 + f], v);
    if (f == 0) {
        float c = lpc[grf];
        if (c != 0.f) atomicAdd(&pcnt[g0 + grf], c);
    }
}

// ---------------- head ----------------

__global__ void head_kernel(const float* __restrict__ psum, const float* __restrict__ pcnt,
                            const float* __restrict__ fc1W, const float* __restrict__ fc1b,
                            const float* __restrict__ fc2W, const float* __restrict__ fc2b,
                            float* __restrict__ out) {
    int g = blockIdx.x * blockDim.x + threadIdx.x;
    if (g >= NGRAPHS) return;
    float inv = 1.0f / fmaxf(pcnt[g], 1.0f);
    float gv[32];
#pragma unroll
    for (int k = 0; k < 32; ++k) gv[k] = psum[g * 32 + k] * inv;
    float o = fc2b[0];
#pragma unroll
    for (int j = 0; j < 16; ++j) {
        float h = fc1b[j];
#pragma unroll
        for (int k = 0; k < 32; ++k) h += gv[k] * fc1W[k * 16 + j];
        h = fmaxf(h, 0.f);
        o += h * fc2W[j];
    }
    out[g] = 1.0f / (1.0f + expf(-o));
}

// ---------------- launch ----------------

extern "C" void kernel_launch(void* const* d_in, const int* in_sizes, int n_in,
                              void* d_out, int out_size, void* d_ws, size_t ws_size,
                              hipStream_t stream) {
    const float* x    = (const float*)d_in[0];
    const int*   ei   = (const int*)d_in[1];
    const int*   batch= (const int*)d_in[2];
    const float* W1   = (const float*)d_in[3];
    const float* b1   = (const float*)d_in[4];
    const float* W2   = (const float*)d_in[5];
    const float* b2   = (const float*)d_in[6];
    const float* fc1W = (const float*)d_in[7];
    const float* fc1b = (const float*)d_in[8];
    const float* fc2W = (const float*)d_in[9];
    const float* fc2b = (const float*)d_in[10];
    float* out = (float*)d_out;

    const int* src = ei;
    const int* dst = ei + NEDGES;

    char* wsb = (char*)d_ws;
    int*      bucketCur = (int*)wsb;                 // 2048 B  } zeroed span
    float*    psum      = (float*)(wsb + 2048);      // 131072  }
    float*    pcnt      = (float*)(wsb + 133120);    // 4096    }  -> zero 137216 B
    int*      ebase     = (int*)(wsb + 137216);      // 2048
    float*    dinv      = (float*)(wsb + 139264);    // 400000
    int*      rowptr    = (int*)(wsb + 539264);      // 400000
    int*      rowend    = (int*)(wsb + 939264);      // 400000
    int*      stage     = (int*)(wsb + 1339392);     // 25.1 MB
    int*      entries   = (int*)(wsb + 26456064);    // 12.8 MB
    unsigned* xs        = (unsigned*)(wsb + 39256064);   // 3.2 MB (bf16x2, 32 B rows)
    unsigned* hm2f      = (unsigned*)(wsb + 42456064);   // 3.2 MB (fp8, 32 B rows)

    const int B = 256;
    zero4_kernel<<<(8576 + B - 1) / B, B, 0, stream>>>((int4*)wsb, 8576);

    binA_kernel<<<NCHUNKS, B, 0, stream>>>(src, dst, bucketCur, stage);
    scanE_kernel<<<1, 64, 0, stream>>>(bucketCur, ebase);
    binB_kernel<<<NBUCK, B, 0, stream>>>(bucketCur, ebase, stage, (const float2*)x,
                                         entries, rowptr, rowend, dinv, xs);

    gather1_mlp_kernel<<<NNODES * 8 / B, B, 0, stream>>>(entries, rowptr, rowend, dinv, xs,
                                                         W1, b1, W2, hm2f);
    gather2_pool_kernel<<<NNODES * 8 / B, B, 0, stream>>>(entries, rowptr, rowend, dinv,
                                                          hm2f, (const float4*)b2,
                                                          batch, psum, pcnt);
    head_kernel<<<(NGRAPHS + B - 1) / B, B, 0, stream>>>(psum, pcnt, fc1W, fc1b, fc2W, fc2b, out);
}